// Round 1
// baseline (160.258 us; speedup 1.0000x reference)
//
#include <hip/hip_runtime.h>

#define BB 4
#define MM 1024
#define NN 65536

// ---------------------------------------------------------------------------
// Kernel 1: per-sample nearest predicted point (argmin over M) + histogram
// ---------------------------------------------------------------------------
__global__ __launch_bounds__(256) void k_assign(
    const float* __restrict__ pp, const float* __restrict__ smp,
    int* __restrict__ idx, int* __restrict__ cnt)
{
    __shared__ float4 pts[MM];
    const int b = blockIdx.x >> 6;       // 64 blocks per batch
    const int chunk = blockIdx.x & 63;
    const float* P = pp + b * MM * 3;
    for (int i = threadIdx.x; i < MM; i += 256) {
        float x = P[i * 3 + 0], y = P[i * 3 + 1], z = P[i * 3 + 2];
        float p2 = __fadd_rn(__fadd_rn(__fmul_rn(x, x), __fmul_rn(y, y)), __fmul_rn(z, z));
        pts[i] = make_float4(x, y, z, p2);
    }
    __syncthreads();

    const int n0 = chunk * 1024 + threadIdx.x;
    const float* S = smp + (size_t)b * NN * 3;
    float sx[4], sy[4], sz[4], best[4];
    int bi[4];
#pragma unroll
    for (int k = 0; k < 4; ++k) {
        int n = n0 + k * 256;
        sx[k] = S[n * 3 + 0];
        sy[k] = S[n * 3 + 1];
        sz[k] = S[n * 3 + 2];
        best[k] = 3.4e38f;
        bi[k] = 0;
    }
#pragma unroll 2
    for (int m = 0; m < MM; ++m) {
        float4 p = pts[m];
#pragma unroll
        for (int k = 0; k < 4; ++k) {
            // emulate np fp32: score = pp2 - 2*((sx*px + sy*py) + sz*pz), no fma
            float dot = __fadd_rn(__fadd_rn(__fmul_rn(sx[k], p.x), __fmul_rn(sy[k], p.y)),
                                  __fmul_rn(sz[k], p.z));
            float sc = __fsub_rn(p.w, __fmul_rn(2.0f, dot));
            if (sc < best[k]) { best[k] = sc; bi[k] = m; }
        }
    }
#pragma unroll
    for (int k = 0; k < 4; ++k) {
        int n = n0 + k * 256;
        idx[b * NN + n] = bi[k];
        atomicAdd(&cnt[b * MM + bi[k]], 1);
    }
}

// ---------------------------------------------------------------------------
// Kernel 2: exclusive prefix scan over the B*M = 4096 histogram bins
// ---------------------------------------------------------------------------
__global__ __launch_bounds__(1024) void k_scan(
    const int* __restrict__ cnt, int* __restrict__ offs, int* __restrict__ cursor)
{
    __shared__ int sh[1024];
    const int t = threadIdx.x;
    int c0 = cnt[t * 4 + 0], c1 = cnt[t * 4 + 1], c2 = cnt[t * 4 + 2], c3 = cnt[t * 4 + 3];
    int s = c0 + c1 + c2 + c3;
    sh[t] = s;
    __syncthreads();
    for (int off = 1; off < 1024; off <<= 1) {
        int v = sh[t];
        int w = (t >= off) ? sh[t - off] : 0;
        __syncthreads();
        sh[t] = v + w;
        __syncthreads();
    }
    int base = sh[t] - s;   // exclusive prefix
    offs[t * 4 + 0] = base; cursor[t * 4 + 0] = base; base += c0;
    offs[t * 4 + 1] = base; cursor[t * 4 + 1] = base; base += c1;
    offs[t * 4 + 2] = base; cursor[t * 4 + 2] = base; base += c2;
    offs[t * 4 + 3] = base; cursor[t * 4 + 3] = base;
}

// ---------------------------------------------------------------------------
// Kernel 3: scatter sample ids into cluster-grouped order[]
// ---------------------------------------------------------------------------
__global__ __launch_bounds__(256) void k_scatter(
    const int* __restrict__ idx, int* __restrict__ cursor, int* __restrict__ order)
{
    int g = blockIdx.x * 256 + threadIdx.x;    // flat sample id in [0, B*N)
    int b = g >> 16;
    int m = idx[g];
    int pos = atomicAdd(&cursor[b * MM + m], 1);
    order[pos] = g & (NN - 1);
}

// ---------------------------------------------------------------------------
// Kernel 4: per-cluster (one wave each) quadric sums + eigensolve + outputs
// ---------------------------------------------------------------------------

// Jacobi rotation on symmetric 3x3 stored as named scalars; constant indices only.
#define ROTJ(APP, AQQ, APQ, ARP, ARQ, V0P, V1P, V2P, V0Q, V1Q, V2Q)            \
    do {                                                                       \
        double apq_ = APQ;                                                     \
        if (fabs(apq_) > 1e-300) {                                             \
            double theta_ = (AQQ - APP) / (2.0 * apq_);                        \
            double t_ = 1.0 / (fabs(theta_) + sqrt(theta_ * theta_ + 1.0));    \
            if (theta_ < 0.0) t_ = -t_;                                        \
            double c_ = 1.0 / sqrt(t_ * t_ + 1.0), sn_ = t_ * c_;              \
            APP -= t_ * apq_; AQQ += t_ * apq_; APQ = 0.0;                     \
            double arp_ = ARP, arq_ = ARQ;                                     \
            ARP = c_ * arp_ - sn_ * arq_;                                      \
            ARQ = sn_ * arp_ + c_ * arq_;                                      \
            double x_;                                                         \
            x_ = V0P; V0P = c_ * x_ - sn_ * V0Q; V0Q = sn_ * x_ + c_ * V0Q;    \
            x_ = V1P; V1P = c_ * x_ - sn_ * V1Q; V1Q = sn_ * x_ + c_ * V1Q;    \
            x_ = V2P; V2P = c_ * x_ - sn_ * V2Q; V2Q = sn_ * x_ + c_ * V2Q;    \
        }                                                                      \
    } while (0)

#define CESWAP(EI, EJ, VA, VB, VC, WA, WB, WC)                                 \
    do {                                                                       \
        if (EI < EJ) {                                                         \
            double tt_;                                                        \
            tt_ = EI; EI = EJ; EJ = tt_;                                       \
            tt_ = VA; VA = WA; WA = tt_;                                       \
            tt_ = VB; VB = WB; WB = tt_;                                       \
            tt_ = VC; VC = WC; WC = tt_;                                       \
        }                                                                      \
    } while (0)

__global__ __launch_bounds__(256) void k_cluster(
    const float* __restrict__ pp, const float* __restrict__ smp,
    const float* __restrict__ nrm, const int* __restrict__ offs,
    const int* __restrict__ cnt, const int* __restrict__ order,
    float* __restrict__ out)
{
    const int wave = blockIdx.x * 4 + (threadIdx.x >> 6);   // cluster id in [0, B*M)
    const int lane = threadIdx.x & 63;
    const int b = wave >> 10;
    const int m = wave & (MM - 1);
    const int start = offs[wave];
    const int count = cnt[wave];
    const float* S = smp + (size_t)b * NN * 3;
    const float* Nr = nrm + (size_t)b * NN * 3;

    double q00 = 0, q01 = 0, q02 = 0, q11 = 0, q12 = 0, q22 = 0;
    double nd0 = 0, nd1 = 0, nd2 = 0, s0 = 0, s1 = 0, s2 = 0;
    for (int i = start + lane; i < start + count; i += 64) {
        int n = order[i];
        double sxv = S[n * 3 + 0], syv = S[n * 3 + 1], szv = S[n * 3 + 2];
        double nx = Nr[n * 3 + 0], ny = Nr[n * 3 + 1], nz = Nr[n * 3 + 2];
        double d = -(nx * sxv + ny * syv + nz * szv);
        q00 += nx * nx; q01 += nx * ny; q02 += nx * nz;
        q11 += ny * ny; q12 += ny * nz; q22 += nz * nz;
        nd0 += nx * d; nd1 += ny * d; nd2 += nz * d;
        s0 += nx; s1 += ny; s2 += nz;
    }
#pragma unroll
    for (int o = 32; o > 0; o >>= 1) {
        q00 += __shfl_xor(q00, o); q01 += __shfl_xor(q01, o); q02 += __shfl_xor(q02, o);
        q11 += __shfl_xor(q11, o); q12 += __shfl_xor(q12, o); q22 += __shfl_xor(q22, o);
        nd0 += __shfl_xor(nd0, o); nd1 += __shfl_xor(nd1, o); nd2 += __shfl_xor(nd2, o);
        s0  += __shfl_xor(s0, o);  s1  += __shfl_xor(s1, o);  s2  += __shfl_xor(s2, o);
    }

    double denom = count > 1 ? (double)count : 1.0;
    double A00 = q00 / denom, A01 = q01 / denom, A02 = q02 / denom;
    double A11 = q11 / denom, A12 = q12 / denom, A22 = q22 / denom;
    double mn0 = s0 / denom, mn1 = s1 / denom, mn2 = s2 / denom;
    double bv0 = -nd0 / denom, bv1 = -nd1 / denom, bv2 = -nd2 / denom;
    bool nonvoid = (mn0 * mn0 + mn1 * mn1 + mn2 * mn2) > 0.0;

    double vs0 = 0, vs1 = 0, vs2 = 0;
    if (nonvoid) {
        double a00 = A00, a01 = A01, a02 = A02, a11 = A11, a12 = A12, a22 = A22;
        double v00 = 1, v01 = 0, v02 = 0;
        double v10 = 0, v11 = 1, v12 = 0;
        double v20 = 0, v21 = 0, v22 = 1;
#pragma unroll
        for (int sweep = 0; sweep < 8; ++sweep) {
            // (p,q)=(0,1), r=2
            ROTJ(a00, a11, a01, a02, a12, v00, v10, v20, v01, v11, v21);
            // (p,q)=(0,2), r=1
            ROTJ(a00, a22, a02, a01, a12, v00, v10, v20, v02, v12, v22);
            // (p,q)=(1,2), r=0
            ROTJ(a11, a22, a12, a01, a02, v01, v11, v21, v02, v12, v22);
        }
        double e0 = a00, e1 = a11, e2 = a22;
        // sort descending, carrying eigenvector columns
        CESWAP(e0, e1, v00, v10, v20, v01, v11, v21);
        CESWAP(e0, e2, v00, v10, v20, v02, v12, v22);
        CESWAP(e1, e2, v01, v11, v21, v02, v12, v22);

        double emax = e0 > 1e-20 ? e0 : 1e-20;
        const float* Pp = pp + ((size_t)b * MM + m) * 3;
        double px = Pp[0], py = Pp[1], pz = Pp[2];
        double r0 = bv0 - (A00 * px + A01 * py + A02 * pz);
        double r1 = bv1 - (A01 * px + A11 * py + A12 * pz);
        double r2 = bv2 - (A02 * px + A12 * py + A22 * pz);
        double thr = 0.01 * emax;
        if (e0 > thr) { double w = (v00 * r0 + v10 * r1 + v20 * r2) / e0; vs0 += w * v00; vs1 += w * v10; vs2 += w * v20; }
        if (e1 > thr) { double w = (v01 * r0 + v11 * r1 + v21 * r2) / e1; vs0 += w * v01; vs1 += w * v11; vs2 += w * v21; }
        if (e2 > thr) { double w = (v02 * r0 + v12 * r1 + v22 * r2) / e2; vs0 += w * v02; vs1 += w * v12; vs2 += w * v22; }
        vs0 += px; vs1 += py; vs2 += pz;
    }

    if (lane == 0) {
        // A: (B,M,3,3) at offset 0
        float* Ao = out + (size_t)wave * 9;
        Ao[0] = (float)A00; Ao[1] = (float)A01; Ao[2] = (float)A02;
        Ao[3] = (float)A01; Ao[4] = (float)A11; Ao[5] = (float)A12;
        Ao[6] = (float)A02; Ao[7] = (float)A12; Ao[8] = (float)A22;
        // mean_normals: (B,M,3) at offset B*M*9 = 36864
        float* Mo = out + 36864 + (size_t)wave * 3;
        Mo[0] = (float)mn0; Mo[1] = (float)mn1; Mo[2] = (float)mn2;
        // vstars: (B,M,3) at offset 49152
        float* Vo = out + 49152 + (size_t)wave * 3;
        Vo[0] = (float)vs0; Vo[1] = (float)vs1; Vo[2] = (float)vs2;
        // non_void: (B,M) at offset 61440
        out[61440 + wave] = nonvoid ? 1.0f : 0.0f;
    }
}

// ---------------------------------------------------------------------------
extern "C" void kernel_launch(void* const* d_in, const int* in_sizes, int n_in,
                              void* d_out, int out_size, void* d_ws, size_t ws_size,
                              hipStream_t stream)
{
    const float* pp  = (const float*)d_in[0];   // (B,M,3)
    const float* smp = (const float*)d_in[1];   // (B,N,3)
    const float* nrm = (const float*)d_in[2];   // (B,N,3)
    float* out = (float*)d_out;

    char* ws = (char*)d_ws;
    int* idx    = (int*)ws;                               // B*N
    int* cnt    = (int*)(ws + (size_t)BB * NN * 4);       // B*M
    int* cursor = cnt + BB * MM;                          // B*M
    int* offs   = cursor + BB * MM;                       // B*M
    int* order  = offs + BB * MM;                         // B*N

    hipMemsetAsync(cnt, 0, BB * MM * sizeof(int), stream);
    k_assign<<<256, 256, 0, stream>>>(pp, smp, idx, cnt);
    k_scan<<<1, 1024, 0, stream>>>(cnt, offs, cursor);
    k_scatter<<<(BB * NN) / 256, 256, 0, stream>>>(idx, cursor, order);
    k_cluster<<<(BB * MM) / 4, 256, 0, stream>>>(pp, smp, nrm, offs, cnt, order, out);
}

// Round 3
// 120.566 us; speedup vs baseline: 1.3292x; 1.3292x over previous
//
#include <hip/hip_runtime.h>

#define BB 4
#define MM 1024
#define NN 65536

// ---------------------------------------------------------------------------
// Kernel 1: per-sample nearest predicted point (argmin over M) + histogram
// 1024 blocks x 256 threads, 1 sample/thread -> 4 blocks/CU, 16 waves/CU.
// ---------------------------------------------------------------------------
__global__ __launch_bounds__(256) void k_assign(
    const float* __restrict__ pp, const float* __restrict__ smp,
    int* __restrict__ idx, int* __restrict__ cnt)
{
    __shared__ float4 pts[MM];
    const int b = blockIdx.x >> 8;       // 256 blocks per batch
    const int chunk = blockIdx.x & 255;
    const float* P = pp + b * MM * 3;
    for (int i = threadIdx.x; i < MM; i += 256) {
        float x = P[i * 3 + 0], y = P[i * 3 + 1], z = P[i * 3 + 2];
        float p2 = x * x + y * y + z * z;
        pts[i] = make_float4(x, y, z, p2);
    }
    __syncthreads();

    const int n = chunk * 256 + threadIdx.x;
    const float* S = smp + (size_t)b * NN * 3;
    const float sx = S[n * 3 + 0], sy = S[n * 3 + 1], sz = S[n * 3 + 2];
    const float m2x = -2.0f * sx, m2y = -2.0f * sy, m2z = -2.0f * sz;
    float best = 3.4e38f;
    int bi = 0;
#pragma unroll 4
    for (int m = 0; m < MM; ++m) {
        float4 p = pts[m];
        float sc = fmaf(m2x, p.x, fmaf(m2y, p.y, fmaf(m2z, p.z, p.w)));
        if (sc < best) { best = sc; bi = m; }
    }
    idx[b * NN + n] = bi;
    atomicAdd(&cnt[b * MM + bi], 1);
}

// ---------------------------------------------------------------------------
// Kernel 2: exclusive prefix scan over the B*M = 4096 histogram bins
// ---------------------------------------------------------------------------
__global__ __launch_bounds__(1024) void k_scan(
    const int* __restrict__ cnt, int* __restrict__ offs, int* __restrict__ cursor)
{
    __shared__ int wsum[16];
    const int t = threadIdx.x;
    const int lane = t & 63, wid = t >> 6;
    int c0 = cnt[t * 4 + 0], c1 = cnt[t * 4 + 1], c2 = cnt[t * 4 + 2], c3 = cnt[t * 4 + 3];
    int s = c0 + c1 + c2 + c3;
    // inclusive wave scan of s
    int ps = s;
#pragma unroll
    for (int off = 1; off < 64; off <<= 1) {
        int w = __shfl_up(ps, off);
        if (lane >= off) ps += w;
    }
    if (lane == 63) wsum[wid] = ps;
    __syncthreads();
    if (t == 0) {
        int acc = 0;
#pragma unroll
        for (int i = 0; i < 16; ++i) { int v = wsum[i]; wsum[i] = acc; acc += v; }
    }
    __syncthreads();
    int base = wsum[wid] + (ps - s);   // exclusive prefix of this thread's 4 bins
    offs[t * 4 + 0] = base; cursor[t * 4 + 0] = base; base += c0;
    offs[t * 4 + 1] = base; cursor[t * 4 + 1] = base; base += c1;
    offs[t * 4 + 2] = base; cursor[t * 4 + 2] = base; base += c2;
    offs[t * 4 + 3] = base; cursor[t * 4 + 3] = base;
}

// ---------------------------------------------------------------------------
// Kernel 3: scatter sample ids into cluster-grouped order[]
// ---------------------------------------------------------------------------
__global__ __launch_bounds__(256) void k_scatter(
    const int* __restrict__ idx, int* __restrict__ cursor, int* __restrict__ order)
{
    int g = blockIdx.x * 256 + threadIdx.x;    // flat sample id in [0, B*N)
    int b = g >> 16;
    int m = idx[g];
    int pos = atomicAdd(&cursor[b * MM + m], 1);
    order[pos] = g & (NN - 1);
}

// ---------------------------------------------------------------------------
// Kernel 4: per-cluster (one wave each) quadric sums + eigensolve + outputs
// ---------------------------------------------------------------------------

// Jacobi rotation on symmetric 3x3 stored as named scalars; constant indices only.
#define ROTJ(APP, AQQ, APQ, ARP, ARQ, V0P, V1P, V2P, V0Q, V1Q, V2Q)            \
    do {                                                                       \
        double apq_ = APQ;                                                     \
        if (fabs(apq_) > 1e-300) {                                             \
            double theta_ = (AQQ - APP) / (2.0 * apq_);                        \
            double t_ = 1.0 / (fabs(theta_) + sqrt(theta_ * theta_ + 1.0));    \
            if (theta_ < 0.0) t_ = -t_;                                        \
            double c_ = 1.0 / sqrt(t_ * t_ + 1.0), sn_ = t_ * c_;              \
            APP -= t_ * apq_; AQQ += t_ * apq_; APQ = 0.0;                     \
            double arp_ = ARP, arq_ = ARQ;                                     \
            ARP = c_ * arp_ - sn_ * arq_;                                      \
            ARQ = sn_ * arp_ + c_ * arq_;                                      \
            double x_;                                                         \
            x_ = V0P; V0P = c_ * x_ - sn_ * V0Q; V0Q = sn_ * x_ + c_ * V0Q;    \
            x_ = V1P; V1P = c_ * x_ - sn_ * V1Q; V1Q = sn_ * x_ + c_ * V1Q;    \
            x_ = V2P; V2P = c_ * x_ - sn_ * V2Q; V2Q = sn_ * x_ + c_ * V2Q;    \
        }                                                                      \
    } while (0)

#define CESWAP(EI, EJ, VA, VB, VC, WA, WB, WC)                                 \
    do {                                                                       \
        if (EI < EJ) {                                                         \
            double tt_;                                                        \
            tt_ = EI; EI = EJ; EJ = tt_;                                       \
            tt_ = VA; VA = WA; WA = tt_;                                       \
            tt_ = VB; VB = WB; WB = tt_;                                       \
            tt_ = VC; VC = WC; WC = tt_;                                       \
        }                                                                      \
    } while (0)

__global__ __launch_bounds__(256) void k_cluster(
    const float* __restrict__ pp, const float* __restrict__ smp,
    const float* __restrict__ nrm, const int* __restrict__ offs,
    const int* __restrict__ cnt, const int* __restrict__ order,
    float* __restrict__ out)
{
    const int wave = blockIdx.x * 4 + (threadIdx.x >> 6);   // cluster id in [0, B*M)
    const int lane = threadIdx.x & 63;
    const int b = wave >> 10;
    const int m = wave & (MM - 1);
    const int start = offs[wave];
    const int count = cnt[wave];
    const float* S = smp + (size_t)b * NN * 3;
    const float* Nr = nrm + (size_t)b * NN * 3;

    double q00 = 0, q01 = 0, q02 = 0, q11 = 0, q12 = 0, q22 = 0;
    double nd0 = 0, nd1 = 0, nd2 = 0, s0 = 0, s1 = 0, s2 = 0;
    for (int i = start + lane; i < start + count; i += 64) {
        int n = order[i];
        double sxv = S[n * 3 + 0], syv = S[n * 3 + 1], szv = S[n * 3 + 2];
        double nx = Nr[n * 3 + 0], ny = Nr[n * 3 + 1], nz = Nr[n * 3 + 2];
        double d = -(nx * sxv + ny * syv + nz * szv);
        q00 += nx * nx; q01 += nx * ny; q02 += nx * nz;
        q11 += ny * ny; q12 += ny * nz; q22 += nz * nz;
        nd0 += nx * d; nd1 += ny * d; nd2 += nz * d;
        s0 += nx; s1 += ny; s2 += nz;
    }
#pragma unroll
    for (int o = 32; o > 0; o >>= 1) {
        q00 += __shfl_xor(q00, o); q01 += __shfl_xor(q01, o); q02 += __shfl_xor(q02, o);
        q11 += __shfl_xor(q11, o); q12 += __shfl_xor(q12, o); q22 += __shfl_xor(q22, o);
        nd0 += __shfl_xor(nd0, o); nd1 += __shfl_xor(nd1, o); nd2 += __shfl_xor(nd2, o);
        s0  += __shfl_xor(s0, o);  s1  += __shfl_xor(s1, o);  s2  += __shfl_xor(s2, o);
    }

    double denom = count > 1 ? (double)count : 1.0;
    double A00 = q00 / denom, A01 = q01 / denom, A02 = q02 / denom;
    double A11 = q11 / denom, A12 = q12 / denom, A22 = q22 / denom;
    double mn0 = s0 / denom, mn1 = s1 / denom, mn2 = s2 / denom;
    double bv0 = -nd0 / denom, bv1 = -nd1 / denom, bv2 = -nd2 / denom;
    bool nonvoid = (mn0 * mn0 + mn1 * mn1 + mn2 * mn2) > 0.0;

    double vs0 = 0, vs1 = 0, vs2 = 0;
    if (nonvoid) {
        double a00 = A00, a01 = A01, a02 = A02, a11 = A11, a12 = A12, a22 = A22;
        double v00 = 1, v01 = 0, v02 = 0;
        double v10 = 0, v11 = 1, v12 = 0;
        double v20 = 0, v21 = 0, v22 = 1;
#pragma unroll
        for (int sweep = 0; sweep < 8; ++sweep) {
            ROTJ(a00, a11, a01, a02, a12, v00, v10, v20, v01, v11, v21);
            ROTJ(a00, a22, a02, a01, a12, v00, v10, v20, v02, v12, v22);
            ROTJ(a11, a22, a12, a01, a02, v01, v11, v21, v02, v12, v22);
        }
        double e0 = a00, e1 = a11, e2 = a22;
        CESWAP(e0, e1, v00, v10, v20, v01, v11, v21);
        CESWAP(e0, e2, v00, v10, v20, v02, v12, v22);
        CESWAP(e1, e2, v01, v11, v21, v02, v12, v22);

        double emax = e0 > 1e-20 ? e0 : 1e-20;
        const float* Pp = pp + ((size_t)b * MM + m) * 3;
        double px = Pp[0], py = Pp[1], pz = Pp[2];
        double r0 = bv0 - (A00 * px + A01 * py + A02 * pz);
        double r1 = bv1 - (A01 * px + A11 * py + A12 * pz);
        double r2 = bv2 - (A02 * px + A12 * py + A22 * pz);
        double thr = 0.01 * emax;
        if (e0 > thr) { double w = (v00 * r0 + v10 * r1 + v20 * r2) / e0; vs0 += w * v00; vs1 += w * v10; vs2 += w * v20; }
        if (e1 > thr) { double w = (v01 * r0 + v11 * r1 + v21 * r2) / e1; vs0 += w * v01; vs1 += w * v11; vs2 += w * v21; }
        if (e2 > thr) { double w = (v02 * r0 + v12 * r1 + v22 * r2) / e2; vs0 += w * v02; vs1 += w * v12; vs2 += w * v22; }
        vs0 += px; vs1 += py; vs2 += pz;
    }

    if (lane == 0) {
        float* Ao = out + (size_t)wave * 9;
        Ao[0] = (float)A00; Ao[1] = (float)A01; Ao[2] = (float)A02;
        Ao[3] = (float)A01; Ao[4] = (float)A11; Ao[5] = (float)A12;
        Ao[6] = (float)A02; Ao[7] = (float)A12; Ao[8] = (float)A22;
        float* Mo = out + 36864 + (size_t)wave * 3;
        Mo[0] = (float)mn0; Mo[1] = (float)mn1; Mo[2] = (float)mn2;
        float* Vo = out + 49152 + (size_t)wave * 3;
        Vo[0] = (float)vs0; Vo[1] = (float)vs1; Vo[2] = (float)vs2;
        out[61440 + wave] = nonvoid ? 1.0f : 0.0f;
    }
}

// ---------------------------------------------------------------------------
extern "C" void kernel_launch(void* const* d_in, const int* in_sizes, int n_in,
                              void* d_out, int out_size, void* d_ws, size_t ws_size,
                              hipStream_t stream)
{
    const float* pp  = (const float*)d_in[0];   // (B,M,3)
    const float* smp = (const float*)d_in[1];   // (B,N,3)
    const float* nrm = (const float*)d_in[2];   // (B,N,3)
    float* out = (float*)d_out;

    char* ws = (char*)d_ws;
    int* idx    = (int*)ws;                               // B*N
    int* cnt    = (int*)(ws + (size_t)BB * NN * 4);       // B*M
    int* cursor = cnt + BB * MM;                          // B*M
    int* offs   = cursor + BB * MM;                       // B*M
    int* order  = offs + BB * MM;                         // B*N

    hipMemsetAsync(cnt, 0, BB * MM * sizeof(int), stream);
    k_assign<<<1024, 256, 0, stream>>>(pp, smp, idx, cnt);
    k_scan<<<1, 1024, 0, stream>>>(cnt, offs, cursor);
    k_scatter<<<(BB * NN) / 256, 256, 0, stream>>>(idx, cursor, order);
    k_cluster<<<(BB * MM) / 4, 256, 0, stream>>>(pp, smp, nrm, offs, cnt, order, out);
}